// Round 14
// baseline (123.991 us; speedup 1.0000x reference)
//
#include <hip/hip_runtime.h>

#define TPB  256     // 4 waves, one row per lane
#define RPB  256     // rows per block
#define XDIM 99
#define NJ   26
#define OUTW 78
#define CH   32      // rows per output-flush chunk
#define NCHK (RPB/CH)   // 8

__device__ __forceinline__ float fast_rcp(float a)  { return __builtin_amdgcn_rcpf(a); }
__device__ __forceinline__ float fast_sqrt(float a) { return __builtin_amdgcn_sqrtf(a); }

__device__ __forceinline__ void rodrigues(float ax, float ay, float az, float* R) {
    const float EPS = 1.1920928955078125e-07f;   // np.finfo(np.float32).eps
    float t = fast_sqrt(ax*ax + ay*ay + az*az);
    float inv = fast_rcp(t + EPS);
    float r0 = ax*inv, r1 = ay*inv, r2 = az*inv;
    float s, c;
    __sincosf(t, &s, &c);
    float omc = 1.0f - c;
    float r00 = r0*r0, r11 = r1*r1, r22 = r2*r2;
    float r01 = r0*r1, r02 = r0*r2, r12 = r1*r2;
    R[0] = 1.0f - omc*(r11 + r22);
    R[1] = -s*r2 + omc*r01;
    R[2] =  s*r1 + omc*r02;
    R[3] =  s*r2 + omc*r01;
    R[4] = 1.0f - omc*(r00 + r22);
    R[5] = -s*r0 + omc*r12;
    R[6] = -s*r1 + omc*r02;
    R[7] =  s*r0 + omc*r12;
    R[8] = 1.0f - omc*(r00 + r11);
}

// (256,5): VGPR cap ~102 (R13 measured 84 live set) -> target 20 waves/CU;
// LDS 9984B is far below the per-CU limit, so VGPR is the binder.
__global__ __launch_bounds__(TPB, 5) void skel_fk(const float* __restrict__ x,
                                                  const float* __restrict__ off,
                                                  float* __restrict__ out) {
    __shared__ float tb[CH * OUTW];              // 9984 B, output transpose only
    const int t = threadIdx.x;
    const int row0 = blockIdx.x * RPB;
    // lane-owned row: sequential 26-triplet walk, ~4 touches/64B line
    const float* rp = x + (long long)(row0 + t) * XDIM;

    // slot tables (slot 0 = hip, slots 1..25 follow ORDER)
    constexpr int OFF_IDX[NJ] = {0,1,2,3,4,6,7,8,9,11,12,13,14,15,16,17,18,19,20,22,24,25,26,27,28,30};
    constexpr int PAR[NJ]     = {-1,0,1,2,3,0,5,6,7,0,9,10,11,12,10,14,15,16,17,17,10,20,21,22,23,23};

    float ang[NJ][9];   // compile-time indices -> SSA registers (dead ones eliminated)
    float pp[NJ][3];    // full position vectors, live until this lane's flush chunk

    {
        float R[9];
        rodrigues(rp[3], rp[4], rp[5], R);
        #pragma unroll
        for (int q = 0; q < 9; ++q) ang[0][q] = R[q];
        pp[0][0] = off[0] + rp[0];
        pp[0][1] = off[1] + rp[1];
        pp[0][2] = off[2] + rp[2];
    }

    #pragma unroll
    for (int s = 1; s < NJ; ++s) {
        const int i  = OFF_IDX[s];
        const int pa = PAR[s];
        float L[9];
        rodrigues(rp[3*i+3], rp[3*i+4], rp[3*i+5], L);   // direct gather
        const float o0 = off[3*i], o1 = off[3*i+1], o2 = off[3*i+2];  // uniform
        #pragma unroll
        for (int c = 0; c < 3; ++c)
            pp[s][c] = o0*ang[pa][c] + o1*ang[pa][3+c] + o2*ang[pa][6+c] + pp[pa][c];
        #pragma unroll
        for (int j = 0; j < 3; ++j)
            #pragma unroll
            for (int kk = 0; kk < 3; ++kk)
                ang[s][3*j+kk] = L[3*j+0]*ang[pa][0+kk]
                               + L[3*j+1]*ang[pa][3+kk]
                               + L[3*j+2]*ang[pa][6+kk];
    }

    // ---- output: 8 chunks of 32 rows through LDS transpose; every global
    //      line full, aligned, written exactly once ----
    #pragma unroll
    for (int c = 0; c < NCHK; ++c) {
        if (c) __syncthreads();                  // previous chunk's reads done
        if ((t >> 5) == c) {                     // this chunk's 32 owner lanes
            float* srow = &tb[(t & 31) * OUTW];  // 312B stride: b64 banks 2-way, free
            #pragma unroll
            for (int j = 0; j < 39; ++j) {       // 78 floats as 39 float2
                float2 v;
                v.x = pp[(2*j)   / 3][(2*j)   % 3];   // compile-time indices
                v.y = pp[(2*j+1) / 3][(2*j+1) % 3];
                *reinterpret_cast<float2*>(&srow[2*j]) = v;
            }
        }
        __syncthreads();
        float* ob = out + ((long long)row0 + CH * c) * OUTW;
        #pragma unroll
        for (int j = 0; j < 5; ++j) {            // 1248 float2 = 32 rows x 78 floats
            int m = t + j * TPB;
            if (m < CH * OUTW / 2) {
                float2 v = *reinterpret_cast<const float2*>(&tb[2*m]);
                *reinterpret_cast<float2*>(&ob[2*m]) = v;
            }
        }
    }
}

extern "C" void kernel_launch(void* const* d_in, const int* in_sizes, int n_in,
                              void* d_out, int out_size, void* d_ws, size_t ws_size,
                              hipStream_t stream) {
    const float* x   = (const float*)d_in[0];
    const float* off = (const float*)d_in[1];
    float* out = (float*)d_out;
    const int B = in_sizes[0] / XDIM;      // 262144
    const int grid = B / RPB;              // 1024
    skel_fk<<<grid, TPB, 0, stream>>>(x, off, out);
}

// Round 15
// 40.077 us; speedup vs baseline: 3.0938x; 3.0938x over previous
//
#include <hip/hip_runtime.h>

#define RPB  64      // rows per block = 1 per lane
#define TPB  64      // one wave
#define XDIM 99
#define NJ   26
#define OUTW 78
#define CH   32      // rows per output-transpose chunk

__device__ __forceinline__ float fast_rcp(float a)  { return __builtin_amdgcn_rcpf(a); }
__device__ __forceinline__ float fast_sqrt(float a) { return __builtin_amdgcn_sqrtf(a); }

__device__ __forceinline__ void rodrigues(float ax, float ay, float az, float* R) {
    const float EPS = 1.1920928955078125e-07f;   // np.finfo(np.float32).eps
    float t = fast_sqrt(ax*ax + ay*ay + az*az);
    float inv = fast_rcp(t + EPS);
    float r0 = ax*inv, r1 = ay*inv, r2 = az*inv;
    float s, c;
    __sincosf(t, &s, &c);
    float omc = 1.0f - c;
    float r00 = r0*r0, r11 = r1*r1, r22 = r2*r2;
    float r01 = r0*r1, r02 = r0*r2, r12 = r1*r2;
    R[0] = 1.0f - omc*(r11 + r22);
    R[1] = -s*r2 + omc*r01;
    R[2] =  s*r1 + omc*r02;
    R[3] =  s*r2 + omc*r01;
    R[4] = 1.0f - omc*(r00 + r22);
    R[5] = -s*r0 + omc*r12;
    R[6] = -s*r1 + omc*r02;
    R[7] =  s*r0 + omc*r12;
    R[8] = 1.0f - omc*(r00 + r11);
}

// (64,5): VGPR cap ~102 — R13's live set measured 84, +12 prefetch regs fits.
__global__ __launch_bounds__(TPB, 5) void skel_fk(const float* __restrict__ x,
                                                  const float* __restrict__ off,
                                                  float* __restrict__ out) {
    __shared__ float tb[CH * OUTW];              // 9984 B, output transpose only
    const int l = threadIdx.x;
    const int row0 = blockIdx.x * RPB;
    const float* rp = x + (long long)(row0 + l) * XDIM;   // lane-owned row

    // slot tables (slot 0 = hip, slots 1..25 follow ORDER)
    constexpr int OFF_IDX[NJ] = {0,1,2,3,4,6,7,8,9,11,12,13,14,15,16,17,18,19,20,22,24,25,26,27,28,30};
    constexpr int PAR[NJ]     = {-1,0,1,2,3,0,5,6,7,0,9,10,11,12,10,14,15,16,17,17,10,20,21,22,23,23};

    float ang[NJ][9];   // compile-time indices -> SSA registers (dead ones eliminated)
    float pp[NJ][3];    // full position vectors, live until flush (proven 84-reg set)

    {
        float R[9];
        rodrigues(rp[3], rp[4], rp[5], R);
        #pragma unroll
        for (int q = 0; q < 9; ++q) ang[0][q] = R[q];
        pp[0][0] = off[0] + rp[0];
        pp[0][1] = off[1] + rp[1];
        pp[0][2] = off[2] + rp[2];
    }

    // 4-deep rolling global prefetch: slot s's triplet loads issue ~4 chain-steps
    // (~360 cyc) before use, covering L2-hit latency. Parity-indexed, fully
    // unrolled -> all indices compile-time -> registers (rule #20 safe).
    float pf[4][3];
    #pragma unroll
    for (int s = 1; s <= 4; ++s) {
        const int c = 3*OFF_IDX[s] + 3;
        pf[s & 3][0] = rp[c]; pf[s & 3][1] = rp[c+1]; pf[s & 3][2] = rp[c+2];
    }

    #pragma unroll
    for (int s = 1; s < NJ; ++s) {
        const int i  = OFF_IDX[s];
        const int pa = PAR[s];
        const float ax = pf[s & 3][0], ay = pf[s & 3][1], az = pf[s & 3][2];
        if (s + 4 < NJ) {                        // refill the slot just consumed
            const int cn = 3*OFF_IDX[s+4] + 3;
            pf[s & 3][0] = rp[cn]; pf[s & 3][1] = rp[cn+1]; pf[s & 3][2] = rp[cn+2];
        }
        float L[9];
        rodrigues(ax, ay, az, L);
        const float o0 = off[3*i], o1 = off[3*i+1], o2 = off[3*i+2];  // uniform
        #pragma unroll
        for (int c = 0; c < 3; ++c)
            pp[s][c] = o0*ang[pa][c] + o1*ang[pa][3+c] + o2*ang[pa][6+c] + pp[pa][c];
        #pragma unroll
        for (int j = 0; j < 3; ++j)
            #pragma unroll
            for (int kk = 0; kk < 3; ++kk)
                ang[s][3*j+kk] = L[3*j+0]*ang[pa][0+kk]
                               + L[3*j+1]*ang[pa][3+kk]
                               + L[3*j+2]*ang[pa][6+kk];
    }

    // ---- output: two 32-row chunks through LDS transpose; every global line
    //      full, aligned, written exactly once. Barriers are wave-local. ----
    #pragma unroll
    for (int c = 0; c < 2; ++c) {
        if (c) __syncthreads();                  // chunk-0 reads done
        if ((l >> 5) == c) {
            float* srow = &tb[(l & 31) * OUTW];  // 312B stride: 2-way banks, free
            #pragma unroll
            for (int j = 0; j < 39; ++j) {       // 78 floats as 39 float2
                float2 v;
                v.x = pp[(2*j)   / 3][(2*j)   % 3];   // compile-time indices
                v.y = pp[(2*j+1) / 3][(2*j+1) % 3];
                *reinterpret_cast<float2*>(&srow[2*j]) = v;
            }
        }
        __syncthreads();
        float* ob = out + ((long long)row0 + CH * c) * OUTW;
        #pragma unroll
        for (int j = 0; j < 20; ++j) {           // 1248 float2 = 32 rows x 78
            int m = l + j * TPB;
            if (m < CH * OUTW / 2) {
                float2 v = *reinterpret_cast<const float2*>(&tb[2*m]);
                *reinterpret_cast<float2*>(&ob[2*m]) = v;
            }
        }
    }
}

extern "C" void kernel_launch(void* const* d_in, const int* in_sizes, int n_in,
                              void* d_out, int out_size, void* d_ws, size_t ws_size,
                              hipStream_t stream) {
    const float* x   = (const float*)d_in[0];
    const float* off = (const float*)d_in[1];
    float* out = (float*)d_out;
    const int B = in_sizes[0] / XDIM;      // 262144
    const int grid = B / RPB;              // 4096
    skel_fk<<<grid, TPB, 0, stream>>>(x, off, out);
}